// Round 12
// baseline (250.621 us; speedup 1.0000x reference)
//
#include <hip/hip_runtime.h>

typedef unsigned int uint;
typedef unsigned short ushort;
using short8 = __attribute__((ext_vector_type(8))) short;   // 8 bf16 (4 VGPRs)
using f32x4  = __attribute__((ext_vector_type(4))) float;

#define NHALF 2048
#define DIM   1024
#define MROWS 4096
#define KMED  8388607u
#define NTRI  528            // 32*33/2 lower-triangle 128x128 blocks
#define NHB   2048           // histb blocks
#define NREP  8              // histb global-hist replicas

// workspace layout (bytes)
#define L2_OFF   0ull                          // 64 MB f32 (lower 128-blocks valid only)
#define AH_OFF   67108864ull                   // 8 MB bf16 hi
#define SQ_OFF   (AH_OFF + 8388608ull)         // 16 KB f32 sq norms (exact)
#define GHA_OFF  (SQ_OFF + 16384ull)           // 64 KB: 16384-bin hist of bits 30:17
#define GHB_OFF  (GHA_OFF + 65536ull)          // 64 KB: 8 replicas x 2048-bin hist of bits 16:6
#define SEL_OFF  (GHB_OFF + 65536ull)          // 64 B: sel[0]=prefix sel[1]=rank selF[2]=itb
#define ACC_OFF  (SEL_OFF + 64ull)             // 16 B: double accumulator
#define CNT_OFF  (ACC_OFF + 16ull)             // 32 B: counters (gemm, histb, loss)
#define ZERO_WORDS 32796                       // (64KB+64KB+64+16+32)/4 from GHA_OFF

#define AGLOAD(p) __hip_atomic_load((p), __ATOMIC_RELAXED, __HIP_MEMORY_SCOPE_AGENT)

__device__ __forceinline__ ushort f2bf(float x) {
    uint u = __float_as_uint(x);
    u += 0x7FFFu + ((u >> 16) & 1u);           // RNE
    return (ushort)(u >> 16);
}

// ---------------------------------------------------------------- dispatch 1: zero scratch + f32->bf16 + sqnorm
__global__ __launch_bounds__(256) void convert_kernel(const float* __restrict__ src,
                                                      const float* __restrict__ tgt,
                                                      char* __restrict__ wsb) {
    ushort* ah = (ushort*)(wsb + AH_OFF);
    float*  sq = (float*)(wsb + SQ_OFF);
    uint*   z  = (uint*)(wsb + GHA_OFF);
    int t = threadIdx.x, row = blockIdx.x;
    int g = row * 256 + t;
    if (g < ZERO_WORDS) z[g] = 0;              // zeros hists + sel + acc + counters
    const float* p = (row < NHALF) ? src + (size_t)row * DIM
                                   : tgt + (size_t)(row - NHALF) * DIM;
    float4 v = reinterpret_cast<const float4*>(p)[t];
    float xs[4] = {v.x, v.y, v.z, v.w};
    ushort hh[4];
    float s = 0.0f;
#pragma unroll
    for (int e = 0; e < 4; ++e) { float x = xs[e]; s += x * x; hh[e] = f2bf(x); }
    ushort4 h4; h4.x = hh[0]; h4.y = hh[1]; h4.z = hh[2]; h4.w = hh[3];
    reinterpret_cast<ushort4*>(ah + (size_t)row * DIM)[t] = h4;
    for (int o = 32; o; o >>= 1) s += __shfl_down(s, o);
    __shared__ float red[4];
    if ((t & 63) == 0) red[t >> 6] = s;
    __syncthreads();
    if (t == 0) sq[row] = red[0] + red[1] + red[2] + red[3];
}

// ---------------------------------------------------------------- dispatch 2: MFMA GEMM, LDS-free fragment-direct, + histA + select1 tail
#define LOADA(dst, kt) do {                                                                \
    _Pragma("unroll")                                                                      \
    for (int _m = 0; _m < 4; ++_m)                                                         \
        dst[_m] = *reinterpret_cast<const short8*>(aptr + (size_t)_m * 16 * DIM + (kt) * 32); \
} while (0)
#define LOADB(dst, kt) do {                                                                \
    _Pragma("unroll")                                                                      \
    for (int _n = 0; _n < 4; ++_n)                                                         \
        dst[_n] = *reinterpret_cast<const short8*>(bptr + (size_t)_n * 16 * DIM + (kt) * 32); \
} while (0)
#define MFMA16(fa, fb) do {                                                                \
    _Pragma("unroll")                                                                      \
    for (int _m = 0; _m < 4; ++_m)                                                         \
        _Pragma("unroll")                                                                  \
        for (int _n = 0; _n < 4; ++_n)                                                     \
            acc[_m][_n] = __builtin_amdgcn_mfma_f32_16x16x32_bf16(fa[_m], fb[_n], acc[_m][_n], 0, 0, 0); \
} while (0)

__global__ __launch_bounds__(256) void gemm_kernel(char* __restrict__ wsb) {
    const ushort* ah = (const ushort*)(wsb + AH_OFF);
    const float*  sq = (const float*)(wsb + SQ_OFF);
    float* L2  = (float*)(wsb + L2_OFF);
    uint*  gha = (uint*)(wsb + GHA_OFF);
    uint*  sel = (uint*)(wsb + SEL_OFF);
    uint*  cnt = (uint*)(wsb + CNT_OFF);

    __shared__ uint h[8192];                  // 32 KB: epilogue hist only

    // XCD swizzle (528 = 8*66, bijective) then triangular decode
    int b = (int)blockIdx.x;
    b = (b & 7) * 66 + (b >> 3);
    int bi = (int)((sqrtf(8.0f * (float)b + 1.0f) - 1.0f) * 0.5f);
    while ((bi + 1) * (bi + 2) / 2 <= b) ++bi;
    while (bi * (bi + 1) / 2 > b) --bi;
    int bj = b - bi * (bi + 1) / 2;          // bj <= bi

    int t = threadIdx.x;
    int lane = t & 63, wid = t >> 6;         // 4 waves
    int wm = wid >> 1, wn = wid & 1;         // 2x2 wave grid: 64x64 per wave
    int rowbase = bi * 128, colbase = bj * 128;

    f32x4 acc[4][4] = {};
    int fr = lane & 15, fk = (lane >> 4) * 8;

    // fragment-direct base pointers (16B per lane, contiguous, aligned)
    const ushort* aptr = ah + (size_t)(rowbase + wm * 64 + fr) * DIM + fk;
    const ushort* bptr = ah + (size_t)(colbase + wn * 64 + fr) * DIM + fk;

    // register double-buffered K-loop — NO LDS, NO barriers
    short8 a0[4], b0[4], a1[4], b1[4];
    LOADA(a0, 0); LOADB(b0, 0);
    for (int kt = 0; kt < 32; kt += 2) {
        LOADA(a1, kt + 1); LOADB(b1, kt + 1);
        MFMA16(a0, b0);
        if (kt + 2 < 32) { LOADA(a0, kt + 2); LOADB(b0, kt + 2); }
        MFMA16(a1, b1);
    }

    // ---- epilogue: L2 store + fused 16384-bin hist of bits 30:17 (u16-packed, 32 KB)
    for (int i = t; i < 8192; i += 256) h[i] = 0;
    __syncthreads();

    uint w = (bi == bj) ? 1u : 2u;
    int fq = lane >> 4;
#pragma unroll
    for (int m = 0; m < 4; ++m) {
#pragma unroll
        for (int n = 0; n < 4; ++n) {
            int gj = colbase + wn * 64 + n * 16 + fr;
            float sqj = sq[gj];
#pragma unroll
            for (int r = 0; r < 4; ++r) {
                int gi = rowbase + wm * 64 + m * 16 + fq * 4 + r;
                float v = fmaxf(sq[gi] + sqj - 2.0f * acc[m][n][r], 0.0f);
                L2[(size_t)gi * MROWS + gj] = v;
                uint k14 = __float_as_uint(v) >> 17;      // <16384 always (bit31==0)
                atomicAdd(&h[k14 >> 1], (k14 & 1) ? (w << 16) : w);
            }
        }
    }
    __syncthreads();
    for (int i = t; i < 8192; i += 256) {      // flush nonzero bins to global
        uint wd = h[i];
        if (wd) {
            uint lo = wd & 0xFFFFu, hi2 = wd >> 16;
            if (lo)  atomicAdd(&gha[2 * i],     lo);
            if (hi2) atomicAdd(&gha[2 * i + 1], hi2);
        }
    }

    // ---- last-block tail: select1 (threadFenceReduction pattern)
    __syncthreads();
    if (t == 0) {
        __threadfence();
        h[0] = (atomicAdd(&cnt[0], 1u) == gridDim.x - 1) ? 1u : 0u;
    }
    __syncthreads();
    bool last = h[0] != 0;
    __syncthreads();
    if (last) {
        uint* part = h + 16;       // 256
        uint* loc  = h + 272;      // 2
        uint* lin  = h + 288;      // 64
        uint s = 0;
        for (int i = 0; i < 64; ++i) s += AGLOAD(&gha[t * 64 + i]);
        part[t] = s;
        __syncthreads();
        if (t == 0) {
            uint k = KMED, cum = 0; int seg = 0;
            for (; seg < 256; ++seg) { uint c = part[seg]; if (cum + c > k) break; cum += c; }
            loc[0] = (uint)seg; loc[1] = k - cum;
        }
        __syncthreads();
        int seg = (int)loc[0];
        if (t < 64) lin[t] = AGLOAD(&gha[seg * 64 + t]);
        __syncthreads();
        if (t == 0) {
            uint k = loc[1], cum = 0; int bb = 0;
            for (; bb < 64; ++bb) { uint c = lin[bb]; if (cum + c > k) break; cum += c; }
            sel[0] = (uint)(seg * 64 + bb);        // bits 30:17 of median
            sel[1] = k - cum;                      // rank within that bin
        }
    }
}

// ---------------------------------------------------------------- dispatch 3: histB (LDS 2048-bin, bits 16:6, 8-replica flush) + select2 tail
__global__ __launch_bounds__(256) void histb_kernel(char* __restrict__ wsb,
                                                    float* __restrict__ out) {
    const float* L2 = (const float*)(wsb + L2_OFF);
    uint*  ghb  = (uint*)(wsb + GHB_OFF);
    uint*  sel  = (uint*)(wsb + SEL_OFF);
    float* selF = (float*)(wsb + SEL_OFF);
    uint*  cnt  = (uint*)(wsb + CNT_OFF);
    __shared__ uint h[2048];                   // 8 KB LDS hist
    int t = threadIdx.x;
    for (int i = t; i < 2048; i += 256) h[i] = 0;
    __syncthreads();
    uint p14 = sel[0];
    for (int rr = blockIdx.x; rr < NHALF; rr += gridDim.x) {
#pragma unroll
        for (int half = 0; half < 2; ++half) {
            int row = half ? (MROWS - 1 - rr) : rr;   // paired rows: constant work/block
            int nc = ((row >> 7) + 1) << 7;           // valid cols (through diag 128-block)
            int diaglo = (row >> 7) << 7;
            const float4* rp = reinterpret_cast<const float4*>(L2 + (size_t)row * MROWS);
            for (int q = t; q < (nc >> 2); q += 256) {
                float4 v = rp[q];
                uint w = ((q << 2) >= diaglo) ? 1u : 2u;
                uint bb[4] = {__float_as_uint(v.x), __float_as_uint(v.y),
                              __float_as_uint(v.z), __float_as_uint(v.w)};
#pragma unroll
                for (int e = 0; e < 4; ++e)
                    if ((bb[e] >> 17) == p14)
                        atomicAdd(&h[(bb[e] >> 6) & 0x7FFu], w);
            }
        }
    }
    __syncthreads();
    {   // flush nonzero bins to this block's replica
        uint* rep = ghb + (blockIdx.x & (NREP - 1)) * 2048;
        for (int i = t; i < 2048; i += 256) {
            uint c = h[i];
            if (c) atomicAdd(&rep[i], c);
        }
    }
    // ---- last-block tail: select2 -> median bin midpoint, bandwidth
    __syncthreads();
    if (t == 0) {
        __threadfence();
        h[0] = (atomicAdd(&cnt[1], 1u) == gridDim.x - 1) ? 1u : 0u;
    }
    __syncthreads();
    bool last = h[0] != 0;
    __syncthreads();
    if (last) {
        uint* part = h + 16;       // 256
        uint* loc  = h + 272;      // 2
        uint* lin  = h + 288;      // 64
        uint s = 0;
#pragma unroll
        for (int r = 0; r < NREP; ++r)
#pragma unroll
            for (int i = 0; i < 8; ++i) s += AGLOAD(&ghb[r * 2048 + t * 8 + i]);
        part[t] = s;
        __syncthreads();
        if (t == 0) {
            uint k = sel[1], cum = 0; int seg = 0;
            for (; seg < 256; ++seg) { uint c = part[seg]; if (cum + c > k) break; cum += c; }
            loc[0] = (uint)seg; loc[1] = k - cum;
        }
        __syncthreads();
        int seg = (int)loc[0];
        if (t < 64) lin[t] = AGLOAD(&ghb[(t >> 3) * 2048 + seg * 8 + (t & 7)]);
        __syncthreads();
        if (t == 0) {
            uint k = loc[1], cum = 0; int bb = 0;
            for (; bb < 8; ++bb) {
                uint c = 0;
#pragma unroll
                for (int r = 0; r < NREP; ++r) c += lin[r * 8 + bb];
                if (cum + c > k) break; cum += c;
            }
            // median resolved to bits >= 6; take bin midpoint (err <= 32 ulp ~ 8e-3 abs)
            uint mbits = (sel[0] << 17) | ((uint)(seg * 8 + bb) << 6) | 32u;
            float median = __uint_as_float(mbits);
            float logn = logf(2048.0f + 1e-8f);
            float bw = sqrtf(0.5f * median / logn);
            out[1] = bw;                               // bandwidth
            selF[2] = logn / median;                   // 1/(2 bw^2)
        }
    }
}

// ---------------------------------------------------------------- dispatch 4: loss reduce + last-block finalize
__global__ __launch_bounds__(256) void loss_kernel(char* __restrict__ wsb,
                                                   float* __restrict__ out) {
    const float* L2   = (const float*)(wsb + L2_OFF);
    const float* selF = (const float*)(wsb + SEL_OFF);
    double* accd = (double*)(wsb + ACC_OFF);
    uint*   cnt  = (uint*)(wsb + CNT_OFF);
    __shared__ float fred[4];
    __shared__ uint flag;
    float itb = selF[2];                       // 1/(2 bw^2)
    int t = threadIdx.x;
    float local = 0.0f;
    for (int rr = blockIdx.x; rr < NHALF; rr += gridDim.x) {
#pragma unroll
        for (int half = 0; half < 2; ++half) {
            int row = half ? (MROWS - 1 - rr) : rr;
            int nc = ((row >> 7) + 1) << 7;
            int diaglo = (row >> 7) << 7;
            bool rlow = row < NHALF;
            const float4* rp = reinterpret_cast<const float4*>(L2 + (size_t)row * MROWS);
            for (int q = t; q < (nc >> 2); q += 256) {
                float4 v = rp[q];
                int j0 = q << 2;
                float w = (j0 >= diaglo) ? 1.0f : 2.0f;
                float sgn = ((j0 < NHALF) == rlow) ? w : -w;   // NHALF is 128-block aligned
                float s = __expf(-v.x * itb) + __expf(-v.y * itb) +
                          __expf(-v.z * itb) + __expf(-v.w * itb);
                local += sgn * s;
            }
        }
    }
    for (int o = 32; o; o >>= 1) local += __shfl_down(local, o);
    if ((t & 63) == 0) fred[t >> 6] = local;
    __syncthreads();
    if (t == 0) {
        atomicAdd(accd, (double)(fred[0] + fred[1] + fred[2] + fred[3]));
        __threadfence();
        flag = (atomicAdd(&cnt[2], 1u) == gridDim.x - 1) ? 1u : 0u;
    }
    __syncthreads();
    if (flag && t == 0) {
        double a = __hip_atomic_load(accd, __ATOMIC_RELAXED, __HIP_MEMORY_SCOPE_AGENT);
        out[0] = (float)(a / 4194304.0);       // mean over N*N, N=2048
    }
}

// ---------------------------------------------------------------- launch (4 dispatches)
extern "C" void kernel_launch(void* const* d_in, const int* in_sizes, int n_in,
                              void* d_out, int out_size, void* d_ws, size_t ws_size,
                              hipStream_t stream) {
    const float* src = (const float*)d_in[0];
    const float* tgt = (const float*)d_in[1];
    float* out = (float*)d_out;
    char* ws = (char*)d_ws;

    convert_kernel<<<MROWS, 256, 0, stream>>>(src, tgt, ws);
    gemm_kernel<<<NTRI, 256, 0, stream>>>(ws);
    histb_kernel<<<NHB, 256, 0, stream>>>(ws, out);
    loss_kernel<<<2048, 256, 0, stream>>>(ws, out);
}

// Round 13
// 160.602 us; speedup vs baseline: 1.5605x; 1.5605x over previous
//
#include <hip/hip_runtime.h>

typedef unsigned int uint;
typedef unsigned short ushort;
using short8 = __attribute__((ext_vector_type(8))) short;   // 8 bf16 (4 VGPRs)
using f32x4  = __attribute__((ext_vector_type(4))) float;

#define NHALF 2048
#define DIM   1024
#define MROWS 4096
#define KMED  8388607u
#define NTRI  528            // 32*33/2 lower-triangle 128x128 blocks

// workspace layout (bytes)
#define L2_OFF   0ull                          // 64 MB f32 (lower 128-blocks valid only)
#define AH_OFF   67108864ull                   // 8 MB bf16 hi
#define SQ_OFF   (AH_OFF + 8388608ull)         // 16 KB f32 sq norms (exact)
#define GHA_OFF  (SQ_OFF + 16384ull)           // 128 KB: 32768-bin hist of bits 30:16
#define SEL_OFF  (GHA_OFF + 131072ull)         // 64 B: selF[2]=itb
#define ACC_OFF  (SEL_OFF + 64ull)             // 16 B: double accumulator
#define CNT_OFF  (ACC_OFF + 16ull)             // 32 B: counters (gemm, loss)
#define ZERO_WORDS 32796                       // (128KB+64+16+32)/4 from GHA_OFF

#define AGLOAD(p) __hip_atomic_load((p), __ATOMIC_RELAXED, __HIP_MEMORY_SCOPE_AGENT)

__device__ __forceinline__ ushort f2bf(float x) {
    uint u = __float_as_uint(x);
    u += 0x7FFFu + ((u >> 16) & 1u);           // RNE
    return (ushort)(u >> 16);
}

// ---------------------------------------------------------------- dispatch 1: zero scratch + f32->bf16 + sqnorm
__global__ __launch_bounds__(256) void convert_kernel(const float* __restrict__ src,
                                                      const float* __restrict__ tgt,
                                                      char* __restrict__ wsb) {
    ushort* ah = (ushort*)(wsb + AH_OFF);
    float*  sq = (float*)(wsb + SQ_OFF);
    uint*   z  = (uint*)(wsb + GHA_OFF);
    int t = threadIdx.x, row = blockIdx.x;
    int g = row * 256 + t;
    if (g < ZERO_WORDS) z[g] = 0;              // zeros hist + sel + acc + counters
    const float* p = (row < NHALF) ? src + (size_t)row * DIM
                                   : tgt + (size_t)(row - NHALF) * DIM;
    float4 v = reinterpret_cast<const float4*>(p)[t];
    float xs[4] = {v.x, v.y, v.z, v.w};
    ushort hh[4];
    float s = 0.0f;
#pragma unroll
    for (int e = 0; e < 4; ++e) { float x = xs[e]; s += x * x; hh[e] = f2bf(x); }
    ushort4 h4; h4.x = hh[0]; h4.y = hh[1]; h4.z = hh[2]; h4.w = hh[3];
    reinterpret_cast<ushort4*>(ah + (size_t)row * DIM)[t] = h4;
    for (int o = 32; o; o >>= 1) s += __shfl_down(s, o);
    __shared__ float red[4];
    if ((t & 63) == 0) red[t >> 6] = s;
    __syncthreads();
    if (t == 0) sq[row] = red[0] + red[1] + red[2] + red[3];
}

// ---------------------------------------------------------------- dispatch 2: MFMA GEMM 128x128, 8 waves, + 15-bit hist + median tail
// stage chunk cidx (16 rows x 32 cols = 1KB) of [buf][arr]
#define STAGE1(buf, arr, srcp, rb, cidx) do {                                              \
    int _i = (cidx) * 64 + lane;                                                           \
    const ushort* _g = (srcp) + ((size_t)((rb) + (_i >> 2)) * DIM + kk0 + (_i & 3) * 8);   \
    __builtin_amdgcn_global_load_lds(                                                      \
        (const __attribute__((address_space(1))) uint*)_g,                                 \
        (__attribute__((address_space(3))) uint*)(&lds[buf][arr][0][0] + (size_t)(cidx) * 512), \
        16, 0, 0);                                                                         \
} while (0)

__global__ __launch_bounds__(512, 4) void gemm_kernel(char* __restrict__ wsb,
                                                      float* __restrict__ out) {
    const ushort* ah = (const ushort*)(wsb + AH_OFF);
    const float*  sq = (const float*)(wsb + SQ_OFF);
    float* L2   = (float*)(wsb + L2_OFF);
    uint*  gha  = (uint*)(wsb + GHA_OFF);
    float* selF = (float*)(wsb + SEL_OFF);
    uint*  cnt  = (uint*)(wsb + CNT_OFF);

    // union: K-loop staging (32 KB) then 32768-bin u16-packed hist (64 KB)
    __shared__ __align__(16) uint shmem[16384];               // 64 KB
    ushort (*lds)[2][128][32] = (ushort (*)[2][128][32])shmem;

    // XCD swizzle (528 = 8*66, bijective) then triangular decode
    int b = (int)blockIdx.x;
    b = (b & 7) * 66 + (b >> 3);
    int bi = (int)((sqrtf(8.0f * (float)b + 1.0f) - 1.0f) * 0.5f);
    while ((bi + 1) * (bi + 2) / 2 <= b) ++bi;
    while (bi * (bi + 1) / 2 > b) --bi;
    int bj = b - bi * (bi + 1) / 2;          // bj <= bi

    int t = threadIdx.x;
    int lane = t & 63, wid = t >> 6;         // 8 waves
    int wm = wid >> 2, wn = wid & 3;         // 2x4 wave grid: 64 rows x 32 cols per wave
    int rowbase = bi * 128, colbase = bj * 128;

    f32x4 acc[4][2] = {};
    int fr = lane & 15, fk = (lane >> 4) * 8;

    {   // prologue: stage k-tile 0 into buffer 0 (wave wid stages chunk wid of A and B)
        int kk0 = 0;
        STAGE1(0, 0, ah, rowbase, wid);
        STAGE1(0, 1, ah, colbase, wid);
    }
    __syncthreads();

    int cur = 0;
    for (int kt = 0; kt < 32; ++kt) {
        if (kt < 31) {                        // issue next-tile loads BEFORE compute
            int kk0 = (kt + 1) * 32;
            int nb = cur ^ 1;
            STAGE1(nb, 0, ah, rowbase, wid);
            STAGE1(nb, 1, ah, colbase, wid);
        }
        short8 fa[4], fb[2];
#pragma unroll
        for (int m = 0; m < 4; ++m)
            fa[m] = *reinterpret_cast<const short8*>(&lds[cur][0][wm * 64 + m * 16 + fr][fk]);
#pragma unroll
        for (int n = 0; n < 2; ++n)
            fb[n] = *reinterpret_cast<const short8*>(&lds[cur][1][wn * 32 + n * 16 + fr][fk]);
#pragma unroll
        for (int m = 0; m < 4; ++m)
#pragma unroll
            for (int n = 0; n < 2; ++n)
                acc[m][n] = __builtin_amdgcn_mfma_f32_16x16x32_bf16(fa[m], fb[n], acc[m][n], 0, 0, 0);
        __syncthreads();                      // drains next-tile vmcnt + this tile's readers
        cur ^= 1;
    }

    // ---- epilogue: L2 store + fused 32768-bin hist of bits 30:16 (u16-packed, 64 KB)
    uint* h = shmem;                          // 16384 words
    for (int i = t; i < 16384; i += 512) h[i] = 0;
    __syncthreads();

    uint w = (bi == bj) ? 1u : 2u;
    int fq = lane >> 4;
#pragma unroll
    for (int m = 0; m < 4; ++m) {
#pragma unroll
        for (int n = 0; n < 2; ++n) {
            int gj = colbase + wn * 32 + n * 16 + fr;
            float sqj = sq[gj];
#pragma unroll
            for (int r = 0; r < 4; ++r) {
                int gi = rowbase + wm * 64 + m * 16 + fq * 4 + r;
                float v = fmaxf(sq[gi] + sqj - 2.0f * acc[m][n][r], 0.0f);
                L2[(size_t)gi * MROWS + gj] = v;
                uint k15 = __float_as_uint(v) >> 16;      // <32768 always (bit31==0)
                atomicAdd(&h[k15 >> 1], (k15 & 1) ? (w << 16) : w);
            }
        }
    }
    __syncthreads();
    for (int i = t; i < 16384; i += 512) {     // flush nonzero bins to global
        uint wd = h[i];
        if (wd) {
            uint lo = wd & 0xFFFFu, hi2 = wd >> 16;
            if (lo)  atomicAdd(&gha[2 * i],     lo);
            if (hi2) atomicAdd(&gha[2 * i + 1], hi2);
        }
    }

    // ---- last-block tail: median select -> bandwidth + itb (threadFenceReduction pattern)
    __syncthreads();
    if (t == 0) {
        __threadfence();
        h[0] = (atomicAdd(&cnt[0], 1u) == gridDim.x - 1) ? 1u : 0u;
    }
    __syncthreads();
    bool last = h[0] != 0;
    __syncthreads();
    if (last) {
        uint* part = h + 16;       // 512
        uint* loc  = h + 544;      // 2
        uint* lin  = h + 560;      // 64
        uint s = 0;
        for (int i = 0; i < 64; ++i) s += AGLOAD(&gha[t * 64 + i]);   // 512 thr x 64 bins
        part[t] = s;
        __syncthreads();
        if (t == 0) {
            uint k = KMED, cum = 0; int seg = 0;
            for (; seg < 512; ++seg) { uint c = part[seg]; if (cum + c > k) break; cum += c; }
            loc[0] = (uint)seg; loc[1] = k - cum;
        }
        __syncthreads();
        int seg = (int)loc[0];
        if (t < 64) lin[t] = AGLOAD(&gha[seg * 64 + t]);
        __syncthreads();
        if (t == 0) {
            uint k = loc[1], cum = 0; int bb = 0;
            for (; bb < 64; ++bb) { uint c = lin[bb]; if (cum + c > k) break; cum += c; }
            // median resolved to bits >= 16; take bin midpoint (err <= 8 abs @ ~2048)
            uint mbits = ((uint)(seg * 64 + bb) << 16) | 0x8000u;
            float median = __uint_as_float(mbits);
            float logn = logf(2048.0f + 1e-8f);
            float bw = sqrtf(0.5f * median / logn);
            out[1] = bw;                               // bandwidth
            selF[2] = logn / median;                   // 1/(2 bw^2)
        }
    }
}

// ---------------------------------------------------------------- dispatch 3: loss reduce + last-block finalize
__global__ __launch_bounds__(256) void loss_kernel(char* __restrict__ wsb,
                                                   float* __restrict__ out) {
    const float* L2   = (const float*)(wsb + L2_OFF);
    const float* selF = (const float*)(wsb + SEL_OFF);
    double* accd = (double*)(wsb + ACC_OFF);
    uint*   cnt  = (uint*)(wsb + CNT_OFF);
    __shared__ float fred[4];
    __shared__ uint flag;
    float itb = selF[2];                       // 1/(2 bw^2)
    int t = threadIdx.x;
    float local = 0.0f;
    for (int rr = blockIdx.x; rr < NHALF; rr += gridDim.x) {
#pragma unroll
        for (int half = 0; half < 2; ++half) {
            int row = half ? (MROWS - 1 - rr) : rr;   // paired rows: constant work/block
            int nc = ((row >> 7) + 1) << 7;
            int diaglo = (row >> 7) << 7;
            bool rlow = row < NHALF;
            const float4* rp = reinterpret_cast<const float4*>(L2 + (size_t)row * MROWS);
            for (int q = t; q < (nc >> 2); q += 256) {
                float4 v = rp[q];
                int j0 = q << 2;
                float w = (j0 >= diaglo) ? 1.0f : 2.0f;
                float sgn = ((j0 < NHALF) == rlow) ? w : -w;   // NHALF is 128-block aligned
                float s = __expf(-v.x * itb) + __expf(-v.y * itb) +
                          __expf(-v.z * itb) + __expf(-v.w * itb);
                local += sgn * s;
            }
        }
    }
    for (int o = 32; o; o >>= 1) local += __shfl_down(local, o);
    if ((t & 63) == 0) fred[t >> 6] = local;
    __syncthreads();
    if (t == 0) {
        atomicAdd(accd, (double)(fred[0] + fred[1] + fred[2] + fred[3]));
        __threadfence();
        flag = (atomicAdd(&cnt[1], 1u) == gridDim.x - 1) ? 1u : 0u;
    }
    __syncthreads();
    if (flag && t == 0) {
        double a = __hip_atomic_load(accd, __ATOMIC_RELAXED, __HIP_MEMORY_SCOPE_AGENT);
        out[0] = (float)(a / 4194304.0);       // mean over N*N, N=2048
    }
}

// ---------------------------------------------------------------- launch (3 dispatches)
extern "C" void kernel_launch(void* const* d_in, const int* in_sizes, int n_in,
                              void* d_out, int out_size, void* d_ws, size_t ws_size,
                              hipStream_t stream) {
    const float* src = (const float*)d_in[0];
    const float* tgt = (const float*)d_in[1];
    float* out = (float*)d_out;
    char* ws = (char*)d_ws;

    convert_kernel<<<MROWS, 256, 0, stream>>>(src, tgt, ws);
    gemm_kernel<<<NTRI, 512, 0, stream>>>(ws, out);
    loss_kernel<<<2048, 256, 0, stream>>>(ws, out);
}

// Round 14
// 134.458 us; speedup vs baseline: 1.8639x; 1.1944x over previous
//
#include <hip/hip_runtime.h>

typedef unsigned int uint;
typedef unsigned short ushort;
using short8 = __attribute__((ext_vector_type(8))) short;   // 8 bf16 (4 VGPRs)
using f32x4  = __attribute__((ext_vector_type(4))) float;

#define NHALF 2048
#define DIM   1024
#define MROWS 4096
#define KMED  8388607u
#define NTRI  528            // 32*33/2 lower-triangle 128x128 blocks

// workspace layout (bytes)
#define L2_OFF   0ull                          // 64 MB f32 (lower 128-blocks valid only)
#define AH_OFF   67108864ull                   // 8 MB bf16 hi
#define SQ_OFF   (AH_OFF + 8388608ull)         // 16 KB f32 sq norms (exact)
#define GHA_OFF  (SQ_OFF + 16384ull)           // 64 KB: 16384-bin hist of bits 29:16 (+1 word low-count)
#define SEL_OFF  (GHA_OFF + 65600ull)          // 64 B: selF[2]=itb
#define ACC_OFF  (SEL_OFF + 64ull)             // 16 B: double accumulator
#define CNT_OFF  (ACC_OFF + 16ull)             // 32 B: counters (gemm, loss)
#define ZERO_WORDS 16428                       // (65600+64+16+32)/4 from GHA_OFF

#define AGLOAD(p) __hip_atomic_load((p), __ATOMIC_RELAXED, __HIP_MEMORY_SCOPE_AGENT)

__device__ __forceinline__ ushort f2bf(float x) {
    uint u = __float_as_uint(x);
    u += 0x7FFFu + ((u >> 16) & 1u);           // RNE
    return (ushort)(u >> 16);
}

// ---------------------------------------------------------------- dispatch 1: zero scratch + f32->bf16 + sqnorm
__global__ __launch_bounds__(256) void convert_kernel(const float* __restrict__ src,
                                                      const float* __restrict__ tgt,
                                                      char* __restrict__ wsb) {
    ushort* ah = (ushort*)(wsb + AH_OFF);
    float*  sq = (float*)(wsb + SQ_OFF);
    uint*   z  = (uint*)(wsb + GHA_OFF);
    int t = threadIdx.x, row = blockIdx.x;
    int g = row * 256 + t;
    if (g < ZERO_WORDS) z[g] = 0;              // zeros hist + low-count + sel + acc + counters
    const float* p = (row < NHALF) ? src + (size_t)row * DIM
                                   : tgt + (size_t)(row - NHALF) * DIM;
    float4 v = reinterpret_cast<const float4*>(p)[t];
    float xs[4] = {v.x, v.y, v.z, v.w};
    ushort hh[4];
    float s = 0.0f;
#pragma unroll
    for (int e = 0; e < 4; ++e) { float x = xs[e]; s += x * x; hh[e] = f2bf(x); }
    ushort4 h4; h4.x = hh[0]; h4.y = hh[1]; h4.z = hh[2]; h4.w = hh[3];
    reinterpret_cast<ushort4*>(ah + (size_t)row * DIM)[t] = h4;
    for (int o = 32; o; o >>= 1) s += __shfl_down(s, o);
    __shared__ float red[4];
    if ((t & 63) == 0) red[t >> 6] = s;
    __syncthreads();
    if (t == 0) sq[row] = red[0] + red[1] + red[2] + red[3];
}

// ---------------------------------------------------------------- dispatch 2: MFMA GEMM 128x128, 8 waves, + bit30-split hist + median tail
// stage chunk cidx (16 rows x 32 cols = 1KB) of [buf][arr]
#define STAGE1(buf, arr, srcp, rb, cidx) do {                                              \
    int _i = (cidx) * 64 + lane;                                                           \
    const ushort* _g = (srcp) + ((size_t)((rb) + (_i >> 2)) * DIM + kk0 + (_i & 3) * 8);   \
    __builtin_amdgcn_global_load_lds(                                                      \
        (const __attribute__((address_space(1))) uint*)_g,                                 \
        (__attribute__((address_space(3))) uint*)(&lds[buf][arr][0][0] + (size_t)(cidx) * 512), \
        16, 0, 0);                                                                         \
} while (0)

__global__ __launch_bounds__(512, 4) void gemm_kernel(char* __restrict__ wsb,
                                                      float* __restrict__ out) {
    const ushort* ah = (const ushort*)(wsb + AH_OFF);
    const float*  sq = (const float*)(wsb + SQ_OFF);
    float* L2   = (float*)(wsb + L2_OFF);
    uint*  gha  = (uint*)(wsb + GHA_OFF);
    float* selF = (float*)(wsb + SEL_OFF);
    uint*  cnt  = (uint*)(wsb + CNT_OFF);

    // union: K-loop staging (32 KB) then 16384-bin u16-packed hist (32 KB) + low-count word
    __shared__ __align__(16) uint shmem[8256];                // ~33 KB
    ushort (*lds)[2][128][32] = (ushort (*)[2][128][32])shmem;

    // XCD swizzle (528 = 8*66, bijective) then triangular decode
    int b = (int)blockIdx.x;
    b = (b & 7) * 66 + (b >> 3);
    int bi = (int)((sqrtf(8.0f * (float)b + 1.0f) - 1.0f) * 0.5f);
    while ((bi + 1) * (bi + 2) / 2 <= b) ++bi;
    while (bi * (bi + 1) / 2 > b) --bi;
    int bj = b - bi * (bi + 1) / 2;          // bj <= bi

    int t = threadIdx.x;
    int lane = t & 63, wid = t >> 6;         // 8 waves
    int wm = wid >> 2, wn = wid & 3;         // 2x4 wave grid: 64 rows x 32 cols per wave
    int rowbase = bi * 128, colbase = bj * 128;

    f32x4 acc[4][2] = {};
    int fr = lane & 15, fk = (lane >> 4) * 8;

    {   // prologue: stage k-tile 0 into buffer 0 (wave wid stages chunk wid of A and B)
        int kk0 = 0;
        STAGE1(0, 0, ah, rowbase, wid);
        STAGE1(0, 1, ah, colbase, wid);
    }
    __syncthreads();

    int cur = 0;
    for (int kt = 0; kt < 32; ++kt) {
        if (kt < 31) {                        // issue next-tile loads BEFORE compute
            int kk0 = (kt + 1) * 32;
            int nb = cur ^ 1;
            STAGE1(nb, 0, ah, rowbase, wid);
            STAGE1(nb, 1, ah, colbase, wid);
        }
        short8 fa[4], fb[2];
#pragma unroll
        for (int m = 0; m < 4; ++m)
            fa[m] = *reinterpret_cast<const short8*>(&lds[cur][0][wm * 64 + m * 16 + fr][fk]);
#pragma unroll
        for (int n = 0; n < 2; ++n)
            fb[n] = *reinterpret_cast<const short8*>(&lds[cur][1][wn * 32 + n * 16 + fr][fk]);
#pragma unroll
        for (int m = 0; m < 4; ++m)
#pragma unroll
            for (int n = 0; n < 2; ++n)
                acc[m][n] = __builtin_amdgcn_mfma_f32_16x16x32_bf16(fa[m], fb[n], acc[m][n], 0, 0, 0);
        __syncthreads();                      // drains next-tile vmcnt + this tile's readers
        cur ^= 1;
    }

    // ---- epilogue: L2 store + fused hist.  bit30=1 (value>=2.0): bin = bits[29:16]
    //      (16384 bins, u16-packed, 32 KB); bit30=0: all < median, count in shmem[8192].
    uint* h = shmem;                          // 8192 packed words + low-count at [8192]
    for (int i = t; i < 8256; i += 512) h[i] = 0;
    __syncthreads();

    uint w = (bi == bj) ? 1u : 2u;
    int fq = lane >> 4;
#pragma unroll
    for (int m = 0; m < 4; ++m) {
#pragma unroll
        for (int n = 0; n < 2; ++n) {
            int gj = colbase + wn * 32 + n * 16 + fr;
            float sqj = sq[gj];
#pragma unroll
            for (int r = 0; r < 4; ++r) {
                int gi = rowbase + wm * 64 + m * 16 + fq * 4 + r;
                float v = fmaxf(sq[gi] + sqj - 2.0f * acc[m][n][r], 0.0f);
                L2[(size_t)gi * MROWS + gj] = v;
                uint bits = __float_as_uint(v);
                if (bits & 0x40000000u) {
                    uint k14 = (bits >> 16) & 0x3FFFu;
                    atomicAdd(&h[k14 >> 1], (k14 & 1) ? (w << 16) : w);
                } else {
                    atomicAdd(&h[8192], w);
                }
            }
        }
    }
    __syncthreads();
    for (int i = t; i < 8192; i += 512) {      // flush nonzero bins to global
        uint wd = h[i];
        if (wd) {
            uint lo = wd & 0xFFFFu, hi2 = wd >> 16;
            if (lo)  atomicAdd(&gha[2 * i],     lo);
            if (hi2) atomicAdd(&gha[2 * i + 1], hi2);
        }
    }
    if (t == 0 && h[8192]) atomicAdd(&gha[16384], h[8192]);

    // ---- last-block tail: median select -> bandwidth + itb (threadFenceReduction pattern)
    __syncthreads();
    if (t == 0) {
        __threadfence();
        h[0] = (atomicAdd(&cnt[0], 1u) == gridDim.x - 1) ? 1u : 0u;
    }
    __syncthreads();
    bool last = h[0] != 0;
    __syncthreads();
    if (last) {
        uint* part = h + 16;       // 512
        uint* loc  = h + 544;      // 2
        uint* lin  = h + 560;      // 32
        uint s = 0;
        for (int i = 0; i < 32; ++i) s += AGLOAD(&gha[t * 32 + i]);   // 512 thr x 32 bins
        part[t] = s;
        __syncthreads();
        if (t == 0) {
            uint k = KMED - AGLOAD(&gha[16384]);   // below-2.0 values rank below everything
            uint cum = 0; int seg = 0;
            for (; seg < 512; ++seg) { uint c = part[seg]; if (cum + c > k) break; cum += c; }
            loc[0] = (uint)seg; loc[1] = k - cum;
        }
        __syncthreads();
        int seg = (int)loc[0];
        if (t < 32) lin[t] = AGLOAD(&gha[seg * 32 + t]);
        __syncthreads();
        if (t == 0) {
            uint k = loc[1], cum = 0; int bb = 0;
            for (; bb < 32; ++bb) { uint c = lin[bb]; if (cum + c > k) break; cum += c; }
            // median resolved to bits >= 16; bin midpoint (same resolution as 15-bit hist)
            uint mbits = 0x40000000u | ((uint)(seg * 32 + bb) << 16) | 0x8000u;
            float median = __uint_as_float(mbits);
            float logn = logf(2048.0f + 1e-8f);
            float bw = sqrtf(0.5f * median / logn);
            out[1] = bw;                               // bandwidth
            selF[2] = logn / median;                   // 1/(2 bw^2)
        }
    }
}

// ---------------------------------------------------------------- dispatch 3: loss reduce + last-block finalize
__global__ __launch_bounds__(256) void loss_kernel(char* __restrict__ wsb,
                                                   float* __restrict__ out) {
    const float* L2   = (const float*)(wsb + L2_OFF);
    const float* selF = (const float*)(wsb + SEL_OFF);
    double* accd = (double*)(wsb + ACC_OFF);
    uint*   cnt  = (uint*)(wsb + CNT_OFF);
    __shared__ float fred[4];
    __shared__ uint flag;
    float itb = selF[2];                       // 1/(2 bw^2)
    int t = threadIdx.x;
    float local = 0.0f;
    for (int rr = blockIdx.x; rr < NHALF; rr += gridDim.x) {
#pragma unroll
        for (int half = 0; half < 2; ++half) {
            int row = half ? (MROWS - 1 - rr) : rr;   // paired rows: constant work/block
            int nc = ((row >> 7) + 1) << 7;
            int diaglo = (row >> 7) << 7;
            bool rlow = row < NHALF;
            const float4* rp = reinterpret_cast<const float4*>(L2 + (size_t)row * MROWS);
            for (int q = t; q < (nc >> 2); q += 256) {
                float4 v = rp[q];
                int j0 = q << 2;
                float w = (j0 >= diaglo) ? 1.0f : 2.0f;
                float sgn = ((j0 < NHALF) == rlow) ? w : -w;   // NHALF is 128-block aligned
                float s = __expf(-v.x * itb) + __expf(-v.y * itb) +
                          __expf(-v.z * itb) + __expf(-v.w * itb);
                local += sgn * s;
            }
        }
    }
    for (int o = 32; o; o >>= 1) local += __shfl_down(local, o);
    if ((t & 63) == 0) fred[t >> 6] = local;
    __syncthreads();
    if (t == 0) {
        atomicAdd(accd, (double)(fred[0] + fred[1] + fred[2] + fred[3]));
        __threadfence();
        flag = (atomicAdd(&cnt[1], 1u) == gridDim.x - 1) ? 1u : 0u;
    }
    __syncthreads();
    if (flag && t == 0) {
        double a = __hip_atomic_load(accd, __ATOMIC_RELAXED, __HIP_MEMORY_SCOPE_AGENT);
        out[0] = (float)(a / 4194304.0);       // mean over N*N, N=2048
    }
}

// ---------------------------------------------------------------- launch (3 dispatches)
extern "C" void kernel_launch(void* const* d_in, const int* in_sizes, int n_in,
                              void* d_out, int out_size, void* d_ws, size_t ws_size,
                              hipStream_t stream) {
    const float* src = (const float*)d_in[0];
    const float* tgt = (const float*)d_in[1];
    float* out = (float*)d_out;
    char* ws = (char*)d_ws;

    convert_kernel<<<MROWS, 256, 0, stream>>>(src, tgt, ws);
    gemm_kernel<<<NTRI, 512, 0, stream>>>(ws, out);
    loss_kernel<<<2048, 256, 0, stream>>>(ws, out);
}